// Round 9
// baseline (203.549 us; speedup 1.0000x reference)
//
#include <hip/hip_runtime.h>
#include <hip/hip_bf16.h>

#define N_NODES 100000
#define N_EDGES 1600000
#define N_FEAT  16
#define HIDDEN  128
#define N_GRAPHS 512
#define CAP     64            // slots per node (mean deg 16, P(>63)~0)
#define NBKT    782           // ceil(100000/128) coarse buckets (dst>>7)
#define BN      128           // nodes per bucket
#define CAPB    2560          // edges per bucket cap (mean 2048, +11 sigma)
#define EPB     2000          // edges per k_part block (800 blocks, ~3/CU for latency hiding)

typedef unsigned short ushort_t;
typedef unsigned char uchar_t;
typedef short v8s __attribute__((ext_vector_type(8)));   // 8 bf16 (4 VGPRs)
typedef float v4f __attribute__((ext_vector_type(4)));   // MFMA accumulator
typedef float v2f __attribute__((ext_vector_type(2)));

#if defined(__has_builtin)
#if __has_builtin(__builtin_amdgcn_cvt_pk_f32_fp8) && __has_builtin(__builtin_amdgcn_cvt_pk_fp8_f32)
#define FP8_HW 1
#endif
#endif

__device__ __forceinline__ ushort_t f2bf(float f) {
    __hip_bfloat16 b = __float2bfloat16(f);
    return *(ushort_t*)&b;
}
__device__ __forceinline__ float bf_lo(unsigned u) {
    union { unsigned i; float f; } c; c.i = u << 16; return c.f;
}
__device__ __forceinline__ float bf_hi(unsigned u) {
    union { unsigned i; float f; } c; c.i = u & 0xffff0000u; return c.f;
}

// ---- fp8 e4m3 (OCP e4m3fn) encode/decode. HW path uses gfx950 cvt instrs; fallback is bit-exact scalar.
__device__ __forceinline__ uchar_t f2fp8(float v) {
#ifdef FP8_HW
    return (uchar_t)(__builtin_amdgcn_cvt_pk_fp8_f32(v, 0.0f, 0, false) & 0xff);
#else
    if (!(v > 0.0f)) return 0;
    if (v >= 448.0f) return 0x7E;
    union { float f; unsigned u; } c; c.f = v;
    int e = ((c.u >> 23) & 255) - 127;
    unsigned m = c.u & 0x7fffff;
    if (e >= -6) {
        unsigned mm = m >> 20;
        unsigned rest = m & 0xfffff;
        if (rest > 0x80000u || (rest == 0x80000u && (mm & 1))) mm++;
        if (mm == 8) { mm = 0; e++; if (e > 8) return 0x7E; }
        return (uchar_t)(((e + 7) << 3) | mm);
    } else {
        int q = (int)(v * 512.0f + 0.5f);
        if (q > 7) q = 7;
        return (uchar_t)q;
    }
#endif
}

#ifndef FP8_HW
__device__ __forceinline__ float fp8d(unsigned b) {
    b &= 0xff;
    unsigned s = b >> 7, e = (b >> 3) & 15, m = b & 7;
    float v;
    if (e == 0) v = (float)m * (1.0f / 512.0f);
    else { union { unsigned u; float f; } c; c.u = ((e + 120u) << 23) | (m << 20); v = c.f; }
    return s ? -v : v;
}
#endif

// unpack 8 fp8 (uint2) and accumulate into a[0..7]
__device__ __forceinline__ void fp8x8_acc(uint2 v, float* a) {
#ifdef FP8_HW
    v2f p0 = __builtin_amdgcn_cvt_pk_f32_fp8(v.x, false);
    v2f p1 = __builtin_amdgcn_cvt_pk_f32_fp8(v.x, true);
    v2f p2 = __builtin_amdgcn_cvt_pk_f32_fp8(v.y, false);
    v2f p3 = __builtin_amdgcn_cvt_pk_f32_fp8(v.y, true);
    a[0] += p0[0]; a[1] += p0[1]; a[2] += p1[0]; a[3] += p1[1];
    a[4] += p2[0]; a[5] += p2[1]; a[6] += p3[0]; a[7] += p3[1];
#else
    a[0] += fp8d(v.x);       a[1] += fp8d(v.x >> 8);
    a[2] += fp8d(v.x >> 16); a[3] += fp8d(v.x >> 24);
    a[4] += fp8d(v.y);       a[5] += fp8d(v.y >> 8);
    a[6] += fp8d(v.y >> 16); a[7] += fp8d(v.y >> 24);
#endif
}
// unpack 16 fp8 (uint4) and accumulate into a[0..15]
__device__ __forceinline__ void fp8x16_acc(uint4 v, float* a) {
    uint2 lo; lo.x = v.x; lo.y = v.y;
    uint2 hi; hi.x = v.z; hi.y = v.w;
    fp8x8_acc(lo, a);
    fp8x8_acc(hi, a + 8);
}

// ---------------- phase 1: coarse partition by dst>>7 (+ packB tail blocks) ----------------
// ebuf entry packed: v = src | (dst_local << 17)
// R8: EPB 4000->2000 (800 blocks = ~3/CU, 12 waves/CU) for latency hiding of the
// LDS-atomic + scattered-store chains; per-thread edge count 8 (was 16).

__global__ __launch_bounds__(256) void k_part(const int* __restrict__ src,
                                              const int* __restrict__ dst,
                                              int* __restrict__ bcnt,
                                              int* __restrict__ ebuf,
                                              const float* __restrict__ W2,
                                              ushort_t* __restrict__ Bp) {
    int tid = threadIdx.x;

    if (blockIdx.x >= N_EDGES / EPB) {
        // packB: W2 -> bf16 MFMA B-fragment order
        int idx = (blockIdx.x - N_EDGES / EPB) * 256 + tid;   // 0..16383
        int j = idx & 7;
        int lane = (idx >> 3) & 63;
        int nt = (idx >> 9) & 7;
        int kt = idx >> 12;
        int k = kt * 32 + (lane >> 4) * 8 + j;
        int n = nt * 16 + (lane & 15);
        Bp[idx] = f2bf(W2[k * HIDDEN + n]);
        return;
    }

    __shared__ int h[NBKT];
    __shared__ int base[NBKT];
    __shared__ int r[NBKT];
    int e0 = blockIdx.x * EPB;

    for (int i = tid; i < NBKT; i += 256) { h[i] = 0; r[i] = 0; }
    __syncthreads();

    // EPB=2000: threads 0..207 handle 8 edges, the rest 7
    int nloc = (tid < EPB - 7 * 256) ? 8 : 7;
    int v[8], bb[8];
    #pragma unroll
    for (int k = 0; k < 8; ++k) {
        if (k < nloc) {
            int i = e0 + tid + k * 256;
            int s = src[i], d = dst[i];
            bb[k] = d >> 7;
            v[k] = s | ((d & 127) << 17);
            atomicAdd(&h[bb[k]], 1);
        }
    }
    __syncthreads();

    for (int i = tid; i < NBKT; i += 256)
        base[i] = atomicAdd(&bcnt[i], h[i]);
    __syncthreads();

    #pragma unroll
    for (int k = 0; k < 8; ++k) {
        if (k < nloc) {
            int b = bb[k];
            int pos = base[b] + atomicAdd(&r[b], 1);
            if (pos < CAPB) ebuf[b * CAPB + pos] = v[k];
        }
    }
}

// ---------------- phase 2: per-bucket LDS ranking + fused prescale ----------------
// R8: ranking loop processes 4 edges/thread/iteration via int4 loads -> 4 independent
// load->LDS-atomic->store chains (was 1, fully serialized). Over-read within the
// bucket's CAPB region is safe (CAPB multiple of 4; values discarded).

__global__ __launch_bounds__(256) void k_fill(const int* __restrict__ bcnt,
                                              const int* __restrict__ ebuf,
                                              const float* __restrict__ x,
                                              int* __restrict__ esrc64,
                                              int* __restrict__ cnt,
                                              float* __restrict__ dinv,
                                              ushort_t* __restrict__ xb,
                                              uchar_t* __restrict__ h1q) {
    __shared__ int lcnt[BN];
    int tid = threadIdx.x;
    int b = blockIdx.x;
    int node0 = b << 7;

    if (tid < BN) lcnt[tid] = 0;
    __syncthreads();

    int nE = bcnt[b]; nE = nE > CAPB ? CAPB : nE;
    const int* eb = ebuf + b * CAPB;
    for (int i0 = tid * 4; i0 < nE; i0 += 1024) {
        int4 v4 = *(const int4*)(eb + i0);   // 16B-aligned; may over-read <=3 stale ints (guarded below)
        #pragma unroll
        for (int k = 0; k < 4; ++k) {
            if (i0 + k < nE) {
                int v = (&v4.x)[k];
                int dl = v >> 17;
                int p = atomicAdd(&lcnt[dl], 1);
                if (p < CAP) esrc64[((node0 + dl) << 6) + p] = v & 0x1FFFF;
            }
        }
    }
    __syncthreads();

    if (tid < BN) {
        int node = node0 + tid;
        if (node < N_NODES) {
            int c = lcnt[tid];
            cnt[node] = c;
            dinv[node] = rsqrtf((float)c + 1.0f);
            int cc = c > CAP ? CAP : c;
            int pad = (cc + 7) & ~7;
            for (int p = cc; p < pad; ++p)
                esrc64[(node << 6) + p] = N_NODES;   // sentinel -> zero row
        }
    }

    for (int i = tid; i < BN * N_FEAT; i += 256) {
        int nl = i >> 4;
        int node = node0 + nl;
        if (node < N_NODES) {
            float di = rsqrtf((float)lcnt[nl] + 1.0f);
            xb[node * N_FEAT + (i & 15)] = f2bf(x[node * N_FEAT + (i & 15)] * di);
        }
    }

    if (b == 0) {
        if (tid < N_FEAT) xb[N_NODES * N_FEAT + tid] = 0;                 // xb sentinel row
        if (tid < HIDDEN) h1q[(size_t)N_NODES * HIDDEN + tid] = 0;        // h1q sentinel row (bytes)
    }
}

// ---------------- fused layer-1: wide-row gather (unroll 8) + LDS mm1 -> h1' (fp8) ----------------
// Verified R4/R6 shape: 32 nodes/block, 8 lanes/row, grid 3125 (16-unroll was neutral, reverted).

__global__ __launch_bounds__(256) void k_agg1f(const int* __restrict__ cnt,
                                               const int* __restrict__ esrc64,
                                               const float* __restrict__ dinv,
                                               const ushort_t* __restrict__ xb,
                                               const float* __restrict__ W1,
                                               const float* __restrict__ b1,
                                               uchar_t* __restrict__ h1q) {
    __shared__ float sw[N_FEAT * HIDDEN];   // 8 KB
    __shared__ float sx[32][20];            // 16 feats padded to 20
    __shared__ float sdd[32];
    int tid = threadIdx.x;
    for (int i = tid; i < N_FEAT * HIDDEN; i += 256) sw[i] = W1[i];

    int wv = tid >> 6;
    int sub = (tid >> 3) & 7;    // node within wave
    int l8 = tid & 7;            // uint (2 feats) within row
    int nl = wv * 8 + sub;       // node local 0..31
    int node = blockIdx.x * 32 + nl;
    const unsigned* xr = (const unsigned*)xb;   // row = 8 uints

    int deg = cnt[node]; deg = deg > CAP ? CAP : deg;
    int deg8 = (deg + 7) & ~7;
    int base = node << 6;
    float dd = dinv[node];

    float a0 = 0.0f, a1 = 0.0f;
    for (int j = 0; j < deg8; j += 8) {
        int4 ia = *(const int4*)(esrc64 + base + j);
        int4 ib = *(const int4*)(esrc64 + base + j + 4);
        unsigned u0 = xr[(unsigned)ia.x * 8 + l8];
        unsigned u1 = xr[(unsigned)ia.y * 8 + l8];
        unsigned u2 = xr[(unsigned)ia.z * 8 + l8];
        unsigned u3 = xr[(unsigned)ia.w * 8 + l8];
        unsigned u4 = xr[(unsigned)ib.x * 8 + l8];
        unsigned u5 = xr[(unsigned)ib.y * 8 + l8];
        unsigned u6 = xr[(unsigned)ib.z * 8 + l8];
        unsigned u7 = xr[(unsigned)ib.w * 8 + l8];
        a0 += bf_lo(u0) + bf_lo(u1) + bf_lo(u2) + bf_lo(u3)
            + bf_lo(u4) + bf_lo(u5) + bf_lo(u6) + bf_lo(u7);
        a1 += bf_hi(u0) + bf_hi(u1) + bf_hi(u2) + bf_hi(u3)
            + bf_hi(u4) + bf_hi(u5) + bf_hi(u6) + bf_hi(u7);
    }
    unsigned su = xr[(unsigned)node * 8 + l8];
    a0 = (a0 + bf_lo(su)) * dd;
    a1 = (a1 + bf_hi(su)) * dd;

    sx[nl][2 * l8] = a0;
    sx[nl][2 * l8 + 1] = a1;
    if (l8 == 0) sdd[nl] = dd;
    __syncthreads();

    int f = tid & 127, half = tid >> 7;
    float bias = b1[f];
    float acc[16];
    #pragma unroll
    for (int n = 0; n < 16; ++n) acc[n] = bias;
    #pragma unroll
    for (int k4 = 0; k4 < 4; ++k4) {
        float w0 = sw[(k4 * 4 + 0) * HIDDEN + f];
        float w1 = sw[(k4 * 4 + 1) * HIDDEN + f];
        float w2 = sw[(k4 * 4 + 2) * HIDDEN + f];
        float w3 = sw[(k4 * 4 + 3) * HIDDEN + f];
        #pragma unroll
        for (int n = 0; n < 16; ++n) {
            float4 xv = *(const float4*)(&sx[half * 16 + n][k4 * 4]);
            acc[n] += xv.x * w0 + xv.y * w1 + xv.z * w2 + xv.w * w3;
        }
    }
    int n0 = blockIdx.x * 32 + half * 16;
    #pragma unroll
    for (int n = 0; n < 16; ++n)
        h1q[(size_t)(n0 + n) * HIDDEN + f] =
            f2fp8(sdd[half * 16 + n] * fmaxf(acc[n], 0.0f));
}

// ---------------- fused layer-2: fp8 gather -> LDS -> MFMA mm2 + head ----------------
// Block = 256 threads = 4 INDEPENDENT waves = 64 nodes; 16.9 KB LDS; NO barrier.
// Gather: 8 lanes/row x uint4 (full 128 B row), 8 rows in flight/wave,
// 1-deep pipelined index loads. 16 fp32 accumulators/lane. MFMA phase verified.

__global__ __launch_bounds__(256) void k_l2(const int* __restrict__ cnt,
                                            const int* __restrict__ esrc64,
                                            const float* __restrict__ dinv,
                                            const uchar_t* __restrict__ h1q,
                                            const ushort_t* __restrict__ Bp,
                                            const float* __restrict__ b2,
                                            const float* __restrict__ Wl,
                                            float* __restrict__ snode) {
    __shared__ ushort_t sA[64 * 132];   // 16.9 KB
    int tid = threadIdx.x;
    int wv = tid >> 6, lane = tid & 63;
    int l8 = lane & 7, q3 = lane >> 3;      // 8 lanes/row, 8 rows/wave
    int node0 = blockIdx.x * 64;
    const uint4* h4 = (const uint4*)h1q;    // row = 8 uint4 (128 B)

    for (int p = 0; p < 2; ++p) {
        int nl = wv * 16 + p * 8 + q3;
        int nodeIdx = node0 + nl;
        int node = nodeIdx < N_NODES ? nodeIdx : 0;   // clamp (last block only)
        int deg = cnt[node]; deg = deg > CAP ? CAP : deg;
        int deg8 = (deg + 7) & ~7;
        int base = node << 6;
        float dd = dinv[node];
        float a[16];
        #pragma unroll
        for (int i = 0; i < 16; ++i) a[i] = 0.0f;
        uint4 sv = h4[(unsigned)node * 8 + l8];
        fp8x16_acc(sv, a);

        // 1-deep pipelined index loads (always within this node's 64-slot region)
        int4 ia = *(const int4*)(esrc64 + base);
        int4 ib = *(const int4*)(esrc64 + base + 4);
        for (int j = 0; j < deg8; j += 8) {
            int jn = j + 8; jn = jn > CAP - 8 ? CAP - 8 : jn;
            int4 ian = *(const int4*)(esrc64 + base + jn);
            int4 ibn = *(const int4*)(esrc64 + base + jn + 4);
            uint4 v0 = h4[(unsigned)ia.x * 8 + l8];
            uint4 v1 = h4[(unsigned)ia.y * 8 + l8];
            uint4 v2 = h4[(unsigned)ia.z * 8 + l8];
            uint4 v3 = h4[(unsigned)ia.w * 8 + l8];
            uint4 v4 = h4[(unsigned)ib.x * 8 + l8];
            uint4 v5 = h4[(unsigned)ib.y * 8 + l8];
            uint4 v6 = h4[(unsigned)ib.z * 8 + l8];
            uint4 v7 = h4[(unsigned)ib.w * 8 + l8];
            fp8x16_acc(v0, a);
            fp8x16_acc(v1, a);
            fp8x16_acc(v2, a);
            fp8x16_acc(v3, a);
            fp8x16_acc(v4, a);
            fp8x16_acc(v5, a);
            fp8x16_acc(v6, a);
            fp8x16_acc(v7, a);
            ia = ian; ib = ibn;
        }
        // pack 16 bf16 and store (four 8B stores: row stride 264 B is 8B-aligned)
        #pragma unroll
        for (int g = 0; g < 4; ++g) {
            unsigned r0 = (unsigned)f2bf(a[4 * g + 0] * dd) | ((unsigned)f2bf(a[4 * g + 1] * dd) << 16);
            unsigned r1 = (unsigned)f2bf(a[4 * g + 2] * dd) | ((unsigned)f2bf(a[4 * g + 3] * dd) << 16);
            uint2 w0; w0.x = r0; w0.y = r1;
            *(uint2*)(&sA[nl * 132 + l8 * 16 + g * 4]) = w0;
        }
    }
    // no __syncthreads: wave reads only its own LDS rows (lgkmcnt handled by compiler)

    // phase 2: MFMA. wave wv handles rows wv*16..+15 (the ones it wrote).
    int m = lane & 15, quad = lane >> 4;
    const ushort_t* arow = &sA[(wv * 16 + m) * 132];

    v4f acc[8];
    #pragma unroll
    for (int nt = 0; nt < 8; ++nt) acc[nt] = (v4f){0.f, 0.f, 0.f, 0.f};

    #pragma unroll
    for (int kt = 0; kt < 4; ++kt) {
        union { v8s v; ushort4 q[2]; } au;
        au.q[0] = *(const ushort4*)(arow + kt * 32 + quad * 8);
        au.q[1] = *(const ushort4*)(arow + kt * 32 + quad * 8 + 4);
        #pragma unroll
        for (int nt = 0; nt < 8; ++nt) {
            v8s b = *(const v8s*)(Bp + ((kt * 8 + nt) * 64 + lane) * 8);
            acc[nt] = __builtin_amdgcn_mfma_f32_16x16x32_bf16(au.v, b, acc[nt], 0, 0, 0);
        }
    }

    float part[4] = {0, 0, 0, 0};
    #pragma unroll
    for (int nt = 0; nt < 8; ++nt) {
        float bb = b2[nt * 16 + m];
        float wl = Wl[nt * 16 + m];
        #pragma unroll
        for (int reg = 0; reg < 4; ++reg)
            part[reg] += fmaxf(acc[nt][reg] + bb, 0.0f) * wl;
    }
    int node0b = node0 + wv * 16;
    #pragma unroll
    for (int reg = 0; reg < 4; ++reg) {
        float p = part[reg];
        p += __shfl_xor(p, 1, 64);
        p += __shfl_xor(p, 2, 64);
        p += __shfl_xor(p, 4, 64);
        p += __shfl_xor(p, 8, 64);
        int node = node0b + quad * 4 + reg;
        if (m == 0 && node < N_NODES) snode[node] = p;
    }
}

// ---------------- pooling: out[g] = mean(snode over graph g) + bl ----------------

__global__ __launch_bounds__(256) void k_pool(const float* __restrict__ snode,
                                              const int* __restrict__ batch,
                                              const float* __restrict__ bl,
                                              float* __restrict__ out) {
    int g = blockIdx.x;
    int tid = threadIdx.x;
    __shared__ float sred[4];

    int lo = 0, hi = N_NODES;
    while (lo < hi) { int mid = (lo + hi) >> 1; if (batch[mid] < g) lo = mid + 1; else hi = mid; }
    int start = lo;
    hi = N_NODES;
    while (lo < hi) { int mid = (lo + hi) >> 1; if (batch[mid] < g + 1) lo = mid + 1; else hi = mid; }
    int end = lo;

    float acc = 0.0f;
    for (int n = start + tid; n < end; n += 256) acc += snode[n];

    #pragma unroll
    for (int off = 32; off; off >>= 1) acc += __shfl_down(acc, off, 64);
    int wave = tid >> 6, lane = tid & 63;
    if (lane == 0) sred[wave] = acc;
    __syncthreads();
    if (tid == 0) {
        float s = sred[0] + sred[1] + sred[2] + sred[3];
        float cnt = (float)(end - start);
        out[g] = s / fmaxf(cnt, 1.0f) + bl[0];
    }
}

// ---------------- launch ----------------

extern "C" void kernel_launch(void* const* d_in, const int* in_sizes, int n_in,
                              void* d_out, int out_size, void* d_ws, size_t ws_size,
                              hipStream_t stream) {
    const float* x    = (const float*)d_in[0];
    const int*   src  = (const int*)d_in[1];
    const int*   dst  = src + N_EDGES;
    const int*   batch= (const int*)d_in[2];
    const float* W1   = (const float*)d_in[3];
    const float* b1   = (const float*)d_in[4];
    const float* W2   = (const float*)d_in[5];
    const float* b2   = (const float*)d_in[6];
    const float* Wl   = (const float*)d_in[7];
    const float* bl   = (const float*)d_in[8];
    float* out = (float*)d_out;

    // byte-offset workspace layout, 256 B aligned chunks
    char* w = (char*)d_ws;
    size_t off = 0;
    auto alloc = [&](size_t bytes) { char* p = w + off; off = (off + bytes + 255) & ~(size_t)255; return p; };

    uchar_t* h1q   = (uchar_t*)alloc((size_t)(N_NODES + 1) * HIDDEN);        // 12.8 MB fp8 (+sentinel)
    int*   ebuf    = (int*)alloc((size_t)NBKT * CAPB * 4);                    // 8.0 MB
    ushort_t* xb   = (ushort_t*)alloc((size_t)(N_NODES + 1) * N_FEAT * 2);   // 3.2 MB (+sentinel)
    float* dinv    = (float*)alloc(N_NODES * 4);
    float* snode   = (float*)alloc(N_NODES * 4);
    int*   cnt     = (int*)alloc(N_NODES * 4);
    int*   esrc64  = (int*)alloc((size_t)N_NODES * CAP * 4);                  // 25.6 MB
    ushort_t* Bp   = (ushort_t*)alloc(16384 * 2);                             // 32 KB
    int*   bcnt    = (int*)alloc(NBKT * 4);

    // build: memset bcnt, partition (+packB tail), per-bucket rank (+prescale+sentinels)
    hipMemsetAsync(bcnt, 0, NBKT * sizeof(int), stream);
    k_part<<<N_EDGES / EPB + 64, 256, 0, stream>>>(src, dst, bcnt, ebuf, W2, Bp);
    k_fill<<<NBKT, 256, 0, stream>>>(bcnt, ebuf, x, esrc64, cnt, dinv, xb, h1q);

    // layer 1 fused: wide-row bf16 gather + LDS mm1 -> h1' (fp8)
    k_agg1f<<<N_NODES / 32, 256, 0, stream>>>(cnt, esrc64, dinv, xb, W1, b1, h1q);

    // layer 2 fused: fp8 gather -> private LDS slice -> MFMA (4 independent waves/block)
    k_l2<<<(N_NODES + 63) / 64, 256, 0, stream>>>(cnt, esrc64, dinv, h1q, Bp, b2, Wl, snode);

    // pool + bias
    k_pool<<<N_GRAPHS, 256, 0, stream>>>(snode, batch, bl, out);
}

// Round 10
// 190.121 us; speedup vs baseline: 1.0706x; 1.0706x over previous
//
#include <hip/hip_runtime.h>
#include <hip/hip_bf16.h>

#define N_NODES 100000
#define N_EDGES 1600000
#define N_FEAT  16
#define HIDDEN  128
#define N_GRAPHS 512
#define CAP     64            // slots per node (mean deg 16, P(>63)~0)
#define NBKT    782           // ceil(100000/128) coarse buckets (dst>>7)
#define BN      128           // nodes per bucket
#define CAPB    2560          // edges per bucket cap (mean 2048, +11 sigma)
#define EPB     4000          // edges per k_part block (400 blocks)

typedef unsigned short ushort_t;
typedef unsigned char uchar_t;
typedef short v8s __attribute__((ext_vector_type(8)));   // 8 bf16 (4 VGPRs)
typedef float v4f __attribute__((ext_vector_type(4)));   // MFMA accumulator
typedef float v2f __attribute__((ext_vector_type(2)));

#if defined(__has_builtin)
#if __has_builtin(__builtin_amdgcn_cvt_pk_f32_fp8) && __has_builtin(__builtin_amdgcn_cvt_pk_fp8_f32)
#define FP8_HW 1
#endif
#endif

__device__ __forceinline__ ushort_t f2bf(float f) {
    __hip_bfloat16 b = __float2bfloat16(f);
    return *(ushort_t*)&b;
}
__device__ __forceinline__ float bf_lo(unsigned u) {
    union { unsigned i; float f; } c; c.i = u << 16; return c.f;
}
__device__ __forceinline__ float bf_hi(unsigned u) {
    union { unsigned i; float f; } c; c.i = u & 0xffff0000u; return c.f;
}

// ---- fp8 e4m3 (OCP e4m3fn) encode/decode. HW path uses gfx950 cvt instrs; fallback is bit-exact scalar.
__device__ __forceinline__ uchar_t f2fp8(float v) {
#ifdef FP8_HW
    return (uchar_t)(__builtin_amdgcn_cvt_pk_fp8_f32(v, 0.0f, 0, false) & 0xff);
#else
    if (!(v > 0.0f)) return 0;
    if (v >= 448.0f) return 0x7E;
    union { float f; unsigned u; } c; c.f = v;
    int e = ((c.u >> 23) & 255) - 127;
    unsigned m = c.u & 0x7fffff;
    if (e >= -6) {
        unsigned mm = m >> 20;
        unsigned rest = m & 0xfffff;
        if (rest > 0x80000u || (rest == 0x80000u && (mm & 1))) mm++;
        if (mm == 8) { mm = 0; e++; if (e > 8) return 0x7E; }
        return (uchar_t)(((e + 7) << 3) | mm);
    } else {
        int q = (int)(v * 512.0f + 0.5f);
        if (q > 7) q = 7;
        return (uchar_t)q;
    }
#endif
}

#ifndef FP8_HW
__device__ __forceinline__ float fp8d(unsigned b) {
    b &= 0xff;
    unsigned s = b >> 7, e = (b >> 3) & 15, m = b & 7;
    float v;
    if (e == 0) v = (float)m * (1.0f / 512.0f);
    else { union { unsigned u; float f; } c; c.u = ((e + 120u) << 23) | (m << 20); v = c.f; }
    return s ? -v : v;
}
#endif

// unpack 8 fp8 (uint2) and accumulate into a[0..7]
__device__ __forceinline__ void fp8x8_acc(uint2 v, float* a) {
#ifdef FP8_HW
    v2f p0 = __builtin_amdgcn_cvt_pk_f32_fp8(v.x, false);
    v2f p1 = __builtin_amdgcn_cvt_pk_f32_fp8(v.x, true);
    v2f p2 = __builtin_amdgcn_cvt_pk_f32_fp8(v.y, false);
    v2f p3 = __builtin_amdgcn_cvt_pk_f32_fp8(v.y, true);
    a[0] += p0[0]; a[1] += p0[1]; a[2] += p1[0]; a[3] += p1[1];
    a[4] += p2[0]; a[5] += p2[1]; a[6] += p3[0]; a[7] += p3[1];
#else
    a[0] += fp8d(v.x);       a[1] += fp8d(v.x >> 8);
    a[2] += fp8d(v.x >> 16); a[3] += fp8d(v.x >> 24);
    a[4] += fp8d(v.y);       a[5] += fp8d(v.y >> 8);
    a[6] += fp8d(v.y >> 16); a[7] += fp8d(v.y >> 24);
#endif
}
// unpack 16 fp8 (uint4) and accumulate into a[0..15]
__device__ __forceinline__ void fp8x16_acc(uint4 v, float* a) {
    uint2 lo; lo.x = v.x; lo.y = v.y;
    uint2 hi; hi.x = v.z; hi.y = v.w;
    fp8x8_acc(lo, a);
    fp8x8_acc(hi, a + 8);
}

// ---------------- phase 1: coarse partition by dst>>7 (+ packB tail blocks) ----------------
// ebuf entry packed: v = src | (dst_local << 17)
// R9 change: pass-1 histogram atomicAdd RETURN is the edge's local rank (lr) ->
// pass-3 position = base[b] + lr. Deletes the second LDS-atomic pass (1.6M atomics)
// and the r[] array + zeroing. Identical bucket content; intra-bucket order changes only.

__global__ __launch_bounds__(256) void k_part(const int* __restrict__ src,
                                              const int* __restrict__ dst,
                                              int* __restrict__ bcnt,
                                              int* __restrict__ ebuf,
                                              const float* __restrict__ W2,
                                              ushort_t* __restrict__ Bp) {
    int tid = threadIdx.x;

    if (blockIdx.x >= N_EDGES / EPB) {
        // packB: W2 -> bf16 MFMA B-fragment order
        int idx = (blockIdx.x - N_EDGES / EPB) * 256 + tid;   // 0..16383
        int j = idx & 7;
        int lane = (idx >> 3) & 63;
        int nt = (idx >> 9) & 7;
        int kt = idx >> 12;
        int k = kt * 32 + (lane >> 4) * 8 + j;
        int n = nt * 16 + (lane & 15);
        Bp[idx] = f2bf(W2[k * HIDDEN + n]);
        return;
    }

    __shared__ int h[NBKT];
    __shared__ int base[NBKT];
    int e0 = blockIdx.x * EPB;

    for (int i = tid; i < NBKT; i += 256) h[i] = 0;
    __syncthreads();

    // EPB=4000: threads 0..159 handle 16 edges, the rest 15
    int nloc = (tid < EPB - 15 * 256) ? 16 : 15;
    int v[16], bb[16], lr[16];
    #pragma unroll
    for (int k = 0; k < 16; ++k) {
        if (k < nloc) {
            int i = e0 + tid + k * 256;
            int s = src[i], d = dst[i];
            bb[k] = d >> 7;
            v[k] = s | ((d & 127) << 17);
            lr[k] = atomicAdd(&h[bb[k]], 1);   // local rank within (block, bucket)
        }
    }
    __syncthreads();

    for (int i = tid; i < NBKT; i += 256)
        base[i] = atomicAdd(&bcnt[i], h[i]);
    __syncthreads();

    #pragma unroll
    for (int k = 0; k < 16; ++k) {
        if (k < nloc) {
            int b = bb[k];
            int pos = base[b] + lr[k];
            if (pos < CAPB) ebuf[b * CAPB + pos] = v[k];
        }
    }
}

// ---------------- phase 2: per-bucket LDS ranking + fused prescale ----------------

__global__ __launch_bounds__(256) void k_fill(const int* __restrict__ bcnt,
                                              const int* __restrict__ ebuf,
                                              const float* __restrict__ x,
                                              int* __restrict__ esrc64,
                                              int* __restrict__ cnt,
                                              float* __restrict__ dinv,
                                              ushort_t* __restrict__ xb,
                                              uchar_t* __restrict__ h1q) {
    __shared__ int lcnt[BN];
    int tid = threadIdx.x;
    int b = blockIdx.x;
    int node0 = b << 7;

    if (tid < BN) lcnt[tid] = 0;
    __syncthreads();

    int nE = bcnt[b]; nE = nE > CAPB ? CAPB : nE;
    const int* eb = ebuf + b * CAPB;
    for (int i = tid; i < nE; i += 256) {
        int v = eb[i];
        int dl = v >> 17;
        int p = atomicAdd(&lcnt[dl], 1);
        if (p < CAP) esrc64[((node0 + dl) << 6) + p] = v & 0x1FFFF;
    }
    __syncthreads();

    if (tid < BN) {
        int node = node0 + tid;
        if (node < N_NODES) {
            int c = lcnt[tid];
            cnt[node] = c;
            dinv[node] = rsqrtf((float)c + 1.0f);
            int cc = c > CAP ? CAP : c;
            int pad = (cc + 7) & ~7;
            for (int p = cc; p < pad; ++p)
                esrc64[(node << 6) + p] = N_NODES;   // sentinel -> zero row
        }
    }

    for (int i = tid; i < BN * N_FEAT; i += 256) {
        int nl = i >> 4;
        int node = node0 + nl;
        if (node < N_NODES) {
            float di = rsqrtf((float)lcnt[nl] + 1.0f);
            xb[node * N_FEAT + (i & 15)] = f2bf(x[node * N_FEAT + (i & 15)] * di);
        }
    }

    if (b == 0) {
        if (tid < N_FEAT) xb[N_NODES * N_FEAT + tid] = 0;                 // xb sentinel row
        if (tid < HIDDEN) h1q[(size_t)N_NODES * HIDDEN + tid] = 0;        // h1q sentinel row (bytes)
    }
}

// ---------------- fused layer-1: wide-row gather (unroll 8) + LDS mm1 -> h1' (fp8) ----------------
// Verified R4/R6 shape: 32 nodes/block, 8 lanes/row, grid 3125.

__global__ __launch_bounds__(256) void k_agg1f(const int* __restrict__ cnt,
                                               const int* __restrict__ esrc64,
                                               const float* __restrict__ dinv,
                                               const ushort_t* __restrict__ xb,
                                               const float* __restrict__ W1,
                                               const float* __restrict__ b1,
                                               uchar_t* __restrict__ h1q) {
    __shared__ float sw[N_FEAT * HIDDEN];   // 8 KB
    __shared__ float sx[32][20];            // 16 feats padded to 20
    __shared__ float sdd[32];
    int tid = threadIdx.x;
    for (int i = tid; i < N_FEAT * HIDDEN; i += 256) sw[i] = W1[i];

    int wv = tid >> 6;
    int sub = (tid >> 3) & 7;    // node within wave
    int l8 = tid & 7;            // uint (2 feats) within row
    int nl = wv * 8 + sub;       // node local 0..31
    int node = blockIdx.x * 32 + nl;
    const unsigned* xr = (const unsigned*)xb;   // row = 8 uints

    int deg = cnt[node]; deg = deg > CAP ? CAP : deg;
    int deg8 = (deg + 7) & ~7;
    int base = node << 6;
    float dd = dinv[node];

    float a0 = 0.0f, a1 = 0.0f;
    for (int j = 0; j < deg8; j += 8) {
        int4 ia = *(const int4*)(esrc64 + base + j);
        int4 ib = *(const int4*)(esrc64 + base + j + 4);
        unsigned u0 = xr[(unsigned)ia.x * 8 + l8];
        unsigned u1 = xr[(unsigned)ia.y * 8 + l8];
        unsigned u2 = xr[(unsigned)ia.z * 8 + l8];
        unsigned u3 = xr[(unsigned)ia.w * 8 + l8];
        unsigned u4 = xr[(unsigned)ib.x * 8 + l8];
        unsigned u5 = xr[(unsigned)ib.y * 8 + l8];
        unsigned u6 = xr[(unsigned)ib.z * 8 + l8];
        unsigned u7 = xr[(unsigned)ib.w * 8 + l8];
        a0 += bf_lo(u0) + bf_lo(u1) + bf_lo(u2) + bf_lo(u3)
            + bf_lo(u4) + bf_lo(u5) + bf_lo(u6) + bf_lo(u7);
        a1 += bf_hi(u0) + bf_hi(u1) + bf_hi(u2) + bf_hi(u3)
            + bf_hi(u4) + bf_hi(u5) + bf_hi(u6) + bf_hi(u7);
    }
    unsigned su = xr[(unsigned)node * 8 + l8];
    a0 = (a0 + bf_lo(su)) * dd;
    a1 = (a1 + bf_hi(su)) * dd;

    sx[nl][2 * l8] = a0;
    sx[nl][2 * l8 + 1] = a1;
    if (l8 == 0) sdd[nl] = dd;
    __syncthreads();

    int f = tid & 127, half = tid >> 7;
    float bias = b1[f];
    float acc[16];
    #pragma unroll
    for (int n = 0; n < 16; ++n) acc[n] = bias;
    #pragma unroll
    for (int k4 = 0; k4 < 4; ++k4) {
        float w0 = sw[(k4 * 4 + 0) * HIDDEN + f];
        float w1 = sw[(k4 * 4 + 1) * HIDDEN + f];
        float w2 = sw[(k4 * 4 + 2) * HIDDEN + f];
        float w3 = sw[(k4 * 4 + 3) * HIDDEN + f];
        #pragma unroll
        for (int n = 0; n < 16; ++n) {
            float4 xv = *(const float4*)(&sx[half * 16 + n][k4 * 4]);
            acc[n] += xv.x * w0 + xv.y * w1 + xv.z * w2 + xv.w * w3;
        }
    }
    int n0 = blockIdx.x * 32 + half * 16;
    #pragma unroll
    for (int n = 0; n < 16; ++n)
        h1q[(size_t)(n0 + n) * HIDDEN + f] =
            f2fp8(sdd[half * 16 + n] * fmaxf(acc[n], 0.0f));
}

// ---------------- fused layer-2: fp8 gather -> LDS -> MFMA mm2 + head ----------------
// Block = 256 threads = 4 INDEPENDENT waves = 64 nodes; 16.9 KB LDS; NO barrier.
// Gather: 8 lanes/row x uint4 (full 128 B row), 8 rows in flight/wave,
// 1-deep pipelined index loads. 16 fp32 accumulators/lane. MFMA phase verified.

__global__ __launch_bounds__(256) void k_l2(const int* __restrict__ cnt,
                                            const int* __restrict__ esrc64,
                                            const float* __restrict__ dinv,
                                            const uchar_t* __restrict__ h1q,
                                            const ushort_t* __restrict__ Bp,
                                            const float* __restrict__ b2,
                                            const float* __restrict__ Wl,
                                            float* __restrict__ snode) {
    __shared__ ushort_t sA[64 * 132];   // 16.9 KB
    int tid = threadIdx.x;
    int wv = tid >> 6, lane = tid & 63;
    int l8 = lane & 7, q3 = lane >> 3;      // 8 lanes/row, 8 rows/wave
    int node0 = blockIdx.x * 64;
    const uint4* h4 = (const uint4*)h1q;    // row = 8 uint4 (128 B)

    for (int p = 0; p < 2; ++p) {
        int nl = wv * 16 + p * 8 + q3;
        int nodeIdx = node0 + nl;
        int node = nodeIdx < N_NODES ? nodeIdx : 0;   // clamp (last block only)
        int deg = cnt[node]; deg = deg > CAP ? CAP : deg;
        int deg8 = (deg + 7) & ~7;
        int base = node << 6;
        float dd = dinv[node];
        float a[16];
        #pragma unroll
        for (int i = 0; i < 16; ++i) a[i] = 0.0f;
        uint4 sv = h4[(unsigned)node * 8 + l8];
        fp8x16_acc(sv, a);

        // 1-deep pipelined index loads (always within this node's 64-slot region)
        int4 ia = *(const int4*)(esrc64 + base);
        int4 ib = *(const int4*)(esrc64 + base + 4);
        for (int j = 0; j < deg8; j += 8) {
            int jn = j + 8; jn = jn > CAP - 8 ? CAP - 8 : jn;
            int4 ian = *(const int4*)(esrc64 + base + jn);
            int4 ibn = *(const int4*)(esrc64 + base + jn + 4);
            uint4 v0 = h4[(unsigned)ia.x * 8 + l8];
            uint4 v1 = h4[(unsigned)ia.y * 8 + l8];
            uint4 v2 = h4[(unsigned)ia.z * 8 + l8];
            uint4 v3 = h4[(unsigned)ia.w * 8 + l8];
            uint4 v4 = h4[(unsigned)ib.x * 8 + l8];
            uint4 v5 = h4[(unsigned)ib.y * 8 + l8];
            uint4 v6 = h4[(unsigned)ib.z * 8 + l8];
            uint4 v7 = h4[(unsigned)ib.w * 8 + l8];
            fp8x16_acc(v0, a);
            fp8x16_acc(v1, a);
            fp8x16_acc(v2, a);
            fp8x16_acc(v3, a);
            fp8x16_acc(v4, a);
            fp8x16_acc(v5, a);
            fp8x16_acc(v6, a);
            fp8x16_acc(v7, a);
            ia = ian; ib = ibn;
        }
        // pack 16 bf16 and store (four 8B stores: row stride 264 B is 8B-aligned)
        #pragma unroll
        for (int g = 0; g < 4; ++g) {
            unsigned r0 = (unsigned)f2bf(a[4 * g + 0] * dd) | ((unsigned)f2bf(a[4 * g + 1] * dd) << 16);
            unsigned r1 = (unsigned)f2bf(a[4 * g + 2] * dd) | ((unsigned)f2bf(a[4 * g + 3] * dd) << 16);
            uint2 w0; w0.x = r0; w0.y = r1;
            *(uint2*)(&sA[nl * 132 + l8 * 16 + g * 4]) = w0;
        }
    }
    // no __syncthreads: wave reads only its own LDS rows (lgkmcnt handled by compiler)

    // phase 2: MFMA. wave wv handles rows wv*16..+15 (the ones it wrote).
    int m = lane & 15, quad = lane >> 4;
    const ushort_t* arow = &sA[(wv * 16 + m) * 132];

    v4f acc[8];
    #pragma unroll
    for (int nt = 0; nt < 8; ++nt) acc[nt] = (v4f){0.f, 0.f, 0.f, 0.f};

    #pragma unroll
    for (int kt = 0; kt < 4; ++kt) {
        union { v8s v; ushort4 q[2]; } au;
        au.q[0] = *(const ushort4*)(arow + kt * 32 + quad * 8);
        au.q[1] = *(const ushort4*)(arow + kt * 32 + quad * 8 + 4);
        #pragma unroll
        for (int nt = 0; nt < 8; ++nt) {
            v8s b = *(const v8s*)(Bp + ((kt * 8 + nt) * 64 + lane) * 8);
            acc[nt] = __builtin_amdgcn_mfma_f32_16x16x32_bf16(au.v, b, acc[nt], 0, 0, 0);
        }
    }

    float part[4] = {0, 0, 0, 0};
    #pragma unroll
    for (int nt = 0; nt < 8; ++nt) {
        float bb = b2[nt * 16 + m];
        float wl = Wl[nt * 16 + m];
        #pragma unroll
        for (int reg = 0; reg < 4; ++reg)
            part[reg] += fmaxf(acc[nt][reg] + bb, 0.0f) * wl;
    }
    int node0b = node0 + wv * 16;
    #pragma unroll
    for (int reg = 0; reg < 4; ++reg) {
        float p = part[reg];
        p += __shfl_xor(p, 1, 64);
        p += __shfl_xor(p, 2, 64);
        p += __shfl_xor(p, 4, 64);
        p += __shfl_xor(p, 8, 64);
        int node = node0b + quad * 4 + reg;
        if (m == 0 && node < N_NODES) snode[node] = p;
    }
}

// ---------------- pooling: out[g] = mean(snode over graph g) + bl ----------------

__global__ __launch_bounds__(256) void k_pool(const float* __restrict__ snode,
                                              const int* __restrict__ batch,
                                              const float* __restrict__ bl,
                                              float* __restrict__ out) {
    int g = blockIdx.x;
    int tid = threadIdx.x;
    __shared__ float sred[4];

    int lo = 0, hi = N_NODES;
    while (lo < hi) { int mid = (lo + hi) >> 1; if (batch[mid] < g) lo = mid + 1; else hi = mid; }
    int start = lo;
    hi = N_NODES;
    while (lo < hi) { int mid = (lo + hi) >> 1; if (batch[mid] < g + 1) lo = mid + 1; else hi = mid; }
    int end = lo;

    float acc = 0.0f;
    for (int n = start + tid; n < end; n += 256) acc += snode[n];

    #pragma unroll
    for (int off = 32; off; off >>= 1) acc += __shfl_down(acc, off, 64);
    int wave = tid >> 6, lane = tid & 63;
    if (lane == 0) sred[wave] = acc;
    __syncthreads();
    if (tid == 0) {
        float s = sred[0] + sred[1] + sred[2] + sred[3];
        float cnt = (float)(end - start);
        out[g] = s / fmaxf(cnt, 1.0f) + bl[0];
    }
}

// ---------------- launch ----------------

extern "C" void kernel_launch(void* const* d_in, const int* in_sizes, int n_in,
                              void* d_out, int out_size, void* d_ws, size_t ws_size,
                              hipStream_t stream) {
    const float* x    = (const float*)d_in[0];
    const int*   src  = (const int*)d_in[1];
    const int*   dst  = src + N_EDGES;
    const int*   batch= (const int*)d_in[2];
    const float* W1   = (const float*)d_in[3];
    const float* b1   = (const float*)d_in[4];
    const float* W2   = (const float*)d_in[5];
    const float* b2   = (const float*)d_in[6];
    const float* Wl   = (const float*)d_in[7];
    const float* bl   = (const float*)d_in[8];
    float* out = (float*)d_out;

    // byte-offset workspace layout, 256 B aligned chunks
    char* w = (char*)d_ws;
    size_t off = 0;
    auto alloc = [&](size_t bytes) { char* p = w + off; off = (off + bytes + 255) & ~(size_t)255; return p; };

    uchar_t* h1q   = (uchar_t*)alloc((size_t)(N_NODES + 1) * HIDDEN);        // 12.8 MB fp8 (+sentinel)
    int*   ebuf    = (int*)alloc((size_t)NBKT * CAPB * 4);                    // 8.0 MB
    ushort_t* xb   = (ushort_t*)alloc((size_t)(N_NODES + 1) * N_FEAT * 2);   // 3.2 MB (+sentinel)
    float* dinv    = (float*)alloc(N_NODES * 4);
    float* snode   = (float*)alloc(N_NODES * 4);
    int*   cnt     = (int*)alloc(N_NODES * 4);
    int*   esrc64  = (int*)alloc((size_t)N_NODES * CAP * 4);                  // 25.6 MB
    ushort_t* Bp   = (ushort_t*)alloc(16384 * 2);                             // 32 KB
    int*   bcnt    = (int*)alloc(NBKT * 4);

    // build: memset bcnt, partition (+packB tail), per-bucket rank (+prescale+sentinels)
    hipMemsetAsync(bcnt, 0, NBKT * sizeof(int), stream);
    k_part<<<N_EDGES / EPB + 64, 256, 0, stream>>>(src, dst, bcnt, ebuf, W2, Bp);
    k_fill<<<NBKT, 256, 0, stream>>>(bcnt, ebuf, x, esrc64, cnt, dinv, xb, h1q);

    // layer 1 fused: wide-row bf16 gather + LDS mm1 -> h1' (fp8)
    k_agg1f<<<N_NODES / 32, 256, 0, stream>>>(cnt, esrc64, dinv, xb, W1, b1, h1q);

    // layer 2 fused: fp8 gather -> private LDS slice -> MFMA (4 independent waves/block)
    k_l2<<<(N_NODES + 63) / 64, 256, 0, stream>>>(cnt, esrc64, dinv, h1q, Bp, b2, Wl, snode);

    // pool + bias
    k_pool<<<N_GRAPHS, 256, 0, stream>>>(snode, batch, bl, out);
}